// Round 6
// baseline (555.422 us; speedup 1.0000x reference)
//
#include <hip/hip_runtime.h>
#include <hip/hip_bf16.h>

// r2: I/O fp32. r3: 605us. r4: 407 (k_attn 185, FETCH 160MB). r5: 429 REGRESSED
// (k_attn 212) but XCD-affinity grid cut FETCH to 49MB — prefetch-after-barrier
// caused synchronized load bursts + bottom-barrier vmcnt(0) drain.
// r6: k_attn barrier-free rewrite — K/V read directly from global as B-frags
// (24KB/chunk, L1/L2-resident, 4x redundant but under L2 ceiling); LDS only for
// wave-private Ps; zero __syncthreads in the K-loop.

typedef unsigned short u16;
typedef unsigned int   u32;
typedef __attribute__((ext_vector_type(4))) float          floatx4;
typedef __attribute__((ext_vector_type(8))) short          shortx8;

#define EMB   768
#define SEQ   2048
#define NHEAD 12
#define HDIM  64
#define RPM   4096   // rows per modal (B*N)
#define NROW  8192   // total rows (2 modals)
#define NUNIT 48     // modal*B*H units
#define LDA   40     // padded LDS stride (bf16) for GEMM tiles (BK=32)
#define LDK   72     // padded LDS stride for Ps (64 cols)

__device__ __forceinline__ float bf2f(u16 h) {
  union { u32 u; float f; } v; v.u = ((u32)h) << 16; return v.f;
}
__device__ __forceinline__ u16 f2bf(float f) {            // RNE
  union { float f; u32 u; } v; v.f = f;
  u32 r = v.u + 0x7fffu + ((v.u >> 16) & 1u);
  return (u16)(r >> 16);
}
__device__ __forceinline__ u16 f2bf_tr(float f) {         // truncate (P in [0,1])
  union { float f; u32 u; } v; v.f = f;
  return (u16)(v.u >> 16);
}
__device__ __forceinline__ float swz_max16(float v) {     // max over 16-lane group
  union { float f; int i; } a;
  a.f = v; a.i = __builtin_amdgcn_ds_swizzle(a.i, 0x041F); v = fmaxf(v, a.f);
  a.f = v; a.i = __builtin_amdgcn_ds_swizzle(a.i, 0x081F); v = fmaxf(v, a.f);
  a.f = v; a.i = __builtin_amdgcn_ds_swizzle(a.i, 0x101F); v = fmaxf(v, a.f);
  a.f = v; a.i = __builtin_amdgcn_ds_swizzle(a.i, 0x201F); v = fmaxf(v, a.f);
  return v;
}

// ---------------- prep: split qkv weights fp32 -> bf16 hi/lo, permuted ----------------
__global__ __launch_bounds__(256) void prep_wq(
    const float* __restrict__ wq1, const float* __restrict__ wq2,
    u16* __restrict__ wh, u16* __restrict__ wl)
{
  int bx = blockIdx.x;                  // 0..4607
  int modal = bx / 2304, rowp = bx % 2304;
  int typ = rowp / 768, hd = rowp % 768;
  const float* W = (modal ? wq2 : wq1) + (size_t)(hd * 3 + typ) * EMB;
  size_t dst = (size_t)bx * EMB;
  int t = threadIdx.x;
  #pragma unroll
  for (int i = 0; i < 3; ++i) {
    int e = t + i * 256;
    float v = W[e];
    u16 h = f2bf(v);
    wh[dst + e] = h;
    wl[dst + e] = f2bf(v - bf2f(h));
  }
}

__global__ __launch_bounds__(256) void prep_wp(
    const float* __restrict__ wp1, const float* __restrict__ wp2,
    u16* __restrict__ wh)
{
  int bx = blockIdx.x;                  // 0..1535
  int modal = bx / 768, row = bx % 768;
  const float* W = (modal ? wp2 : wp1) + (size_t)row * EMB;
  size_t dst = (size_t)bx * EMB;
  int t = threadIdx.x;
  #pragma unroll
  for (int i = 0; i < 3; ++i) {
    int e = t + i * 256;
    wh[dst + e] = f2bf(W[e]);
  }
}

// ---------------- Kernel 1: LayerNorm (fp32 in) + hi/lo bf16 split ----------------
__global__ __launch_bounds__(256) void k_ln(
    const float* __restrict__ x1, const float* __restrict__ x2,
    const float* __restrict__ g1, const float* __restrict__ b1,
    const float* __restrict__ g2, const float* __restrict__ b2,
    u16* __restrict__ xn_hi, u16* __restrict__ xn_lo)
{
  int row = blockIdx.x;                 // 0..8191, modal-major
  int modal = row >> 12;
  const float* x = modal ? x2 : x1;
  const float* g = modal ? g2 : g1;
  const float* bb = modal ? b2 : b1;
  int r = row & (RPM - 1);
  const float* xr = x + (size_t)r * EMB;
  int t = threadIdx.x;
  float v0 = xr[t], v1 = xr[t + 256], v2 = xr[t + 512];
  float s = v0 + v1 + v2;
  float s2 = v0 * v0 + v1 * v1 + v2 * v2;
  #pragma unroll
  for (int m = 1; m < 64; m <<= 1) { s += __shfl_xor(s, m); s2 += __shfl_xor(s2, m); }
  __shared__ float ls[4], ls2[4];
  int w = t >> 6;
  if ((t & 63) == 0) { ls[w] = s; ls2[w] = s2; }
  __syncthreads();
  s = ls[0] + ls[1] + ls[2] + ls[3];
  s2 = ls2[0] + ls2[1] + ls2[2] + ls2[3];
  float mu = s * (1.0f / EMB);
  float var = s2 * (1.0f / EMB) - mu * mu;
  float rs = rsqrtf(var + 1e-5f);
  size_t base = (size_t)row * EMB;
  float vv[3] = { v0, v1, v2 };
  #pragma unroll
  for (int i = 0; i < 3; ++i) {
    int e = t + i * 256;
    float xn = (vv[i] - mu) * rs * g[e] + bb[e];
    u16 h = f2bf(xn);
    xn_hi[base + e] = h;
    xn_lo[base + e] = f2bf(xn - bf2f(h));
  }
}

// ---------------- Kernel 2: QKV GEMM (pre-split W, reg-prefetch) ----------------
// grid (32 row-tiles, 18 col-tiles, 2 modals), 256 thr. Tile 128x128, BK=32.
__global__ __launch_bounds__(256) void k_qkv(
    const u16* __restrict__ xn_hi, const u16* __restrict__ xn_lo,
    const u16* __restrict__ wqh, const u16* __restrict__ wql,
    const float* __restrict__ bq1, const float* __restrict__ bq2,
    u16* __restrict__ q_hi, u16* __restrict__ q_lo,
    u16* __restrict__ k_hi, u16* __restrict__ k_lo,
    u16* __restrict__ vT)
{
  int mt = blockIdx.x, ntile = blockIdx.y, modal = blockIdx.z;
  const float* BQ = modal ? bq2 : bq1;
  int typ = ntile / 6;            // 0=q 1=k 2=v
  int hd0 = (ntile % 6) * 128;

  __shared__ u16 As_hi[128 * LDA], As_lo[128 * LDA], Wh[128 * LDA], Wl[128 * LDA];

  int tid = threadIdx.x, lane = tid & 63, w = tid >> 6;
  int wm = (w >> 1) * 64, wn = (w & 1) * 64;
  int lc = lane & 15, lq = lane >> 4;

  floatx4 acc[4][4] = {};
  size_t arow0 = (size_t)(modal * RPM + mt * 128) * EMB;
  size_t wrow0 = (size_t)(modal * 2304 + typ * 768 + hd0) * EMB;

  int c0 = tid, c1 = tid + 256;
  int r0 = c0 >> 2, cc0 = (c0 & 3) * 8;
  int r1 = c1 >> 2, cc1 = (c1 & 3) * 8;
  size_t go0 = (size_t)r0 * EMB + cc0, go1 = (size_t)r1 * EMB + cc1;

  shortx8 pAh0, pAh1, pW0, pW1, pAl0, pAl1, pL0, pL1;
  #define QKV_LOAD(k0) do { \
    pAh0 = *(const shortx8*)(xn_hi + arow0 + go0 + (k0)); \
    pAh1 = *(const shortx8*)(xn_hi + arow0 + go1 + (k0)); \
    pW0  = *(const shortx8*)(wqh + wrow0 + go0 + (k0)); \
    pW1  = *(const shortx8*)(wqh + wrow0 + go1 + (k0)); \
    if (typ != 2) { \
      pAl0 = *(const shortx8*)(xn_lo + arow0 + go0 + (k0)); \
      pAl1 = *(const shortx8*)(xn_lo + arow0 + go1 + (k0)); \
      pL0  = *(const shortx8*)(wql + wrow0 + go0 + (k0)); \
      pL1  = *(const shortx8*)(wql + wrow0 + go1 + (k0)); \
    } } while (0)

  QKV_LOAD(0);
  for (int k0 = 0; k0 < EMB; k0 += 32) {
    *(shortx8*)&As_hi[r0 * LDA + cc0] = pAh0;
    *(shortx8*)&As_hi[r1 * LDA + cc1] = pAh1;
    *(shortx8*)&Wh[r0 * LDA + cc0]    = pW0;
    *(shortx8*)&Wh[r1 * LDA + cc1]    = pW1;
    if (typ != 2) {
      *(shortx8*)&As_lo[r0 * LDA + cc0] = pAl0;
      *(shortx8*)&As_lo[r1 * LDA + cc1] = pAl1;
      *(shortx8*)&Wl[r0 * LDA + cc0]    = pL0;
      *(shortx8*)&Wl[r1 * LDA + cc1]    = pL1;
    }
    __syncthreads();
    if (k0 + 32 < EMB) QKV_LOAD(k0 + 32);

    shortx8 ah[4], al[4], wh[4], wl[4];
    #pragma unroll
    for (int i = 0; i < 4; ++i) {
      ah[i] = *(const shortx8*)&As_hi[(wm + i * 16 + lc) * LDA + lq * 8];
      wh[i] = *(const shortx8*)&Wh[(wn + i * 16 + lc) * LDA + lq * 8];
      if (typ != 2) {
        al[i] = *(const shortx8*)&As_lo[(wm + i * 16 + lc) * LDA + lq * 8];
        wl[i] = *(const shortx8*)&Wl[(wn + i * 16 + lc) * LDA + lq * 8];
      }
    }
    #pragma unroll
    for (int i = 0; i < 4; ++i)
      #pragma unroll
      for (int jn = 0; jn < 4; ++jn) {
        acc[i][jn] = __builtin_amdgcn_mfma_f32_16x16x32_bf16(ah[i], wh[jn], acc[i][jn], 0, 0, 0);
        if (typ != 2) {
          acc[i][jn] = __builtin_amdgcn_mfma_f32_16x16x32_bf16(al[i], wh[jn], acc[i][jn], 0, 0, 0);
          acc[i][jn] = __builtin_amdgcn_mfma_f32_16x16x32_bf16(ah[i], wl[jn], acc[i][jn], 0, 0, 0);
        }
      }
    __syncthreads();
  }
  #undef QKV_LOAD

  #pragma unroll
  for (int i = 0; i < 4; ++i) {
    int mrow0 = mt * 128 + wm + i * 16 + lq * 4;
    #pragma unroll
    for (int jn = 0; jn < 4; ++jn) {
      int colp = hd0 + wn + jn * 16 + lc;          // hd index [0,768)
      int h = colp >> 6, d = colp & 63;
      float bias = BQ[colp * 3 + typ];
      #pragma unroll
      for (int r = 0; r < 4; ++r) {
        int mrow = mrow0 + r;
        int b = mrow >> 11, nq = mrow & (SEQ - 1);
        int uu = modal * 24 + b * 12 + h;
        float val = acc[i][jn][r] + bias;
        if (typ == 0) {
          size_t o = ((size_t)uu * SEQ + nq) * HDIM + d;
          u16 hh = f2bf(val); q_hi[o] = hh; q_lo[o] = f2bf(val - bf2f(hh));
        } else if (typ == 1) {
          size_t o = ((size_t)uu * SEQ + nq) * HDIM + d;
          u16 hh = f2bf(val); k_hi[o] = hh; k_lo[o] = f2bf(val - bf2f(hh));
        } else {
          vT[((size_t)uu * HDIM + d) * SEQ + nq] = f2bf(val);
        }
      }
    }
  }
}

// ---------------- Kernel 3: flash attention, BARRIER-FREE ----------------
// grid (48 units, 16 q-tiles): XCD = u%8 fixed -> per-unit K/V L2-resident.
// K/V read directly from global as MFMA B-fragments (24KB/chunk, L1-resident,
// shared across the CU's waves via cache). LDS holds only wave-private Ps.
__global__ __launch_bounds__(256) void k_attn(
    const u16* __restrict__ q_hi, const u16* __restrict__ q_lo,
    const u16* __restrict__ k_hi, const u16* __restrict__ k_lo,
    const u16* __restrict__ vT, u16* __restrict__ attn_out)
{
  int u = blockIdx.x, qt = blockIdx.y;
  __shared__ u16 Ps[4][32 * LDK];

  int tid = threadIdx.x, lane = tid & 63, w = tid >> 6;
  int lc = lane & 15, lq = lane >> 4;
  u16* psw = &Ps[w][0];

  // Q fragments: 2 m-tiles x 2 k-slices, hi+lo (A-layout: m=lc, k=lq*8+j)
  shortx8 qh[2][2], ql[2][2];
  #pragma unroll
  for (int mi = 0; mi < 2; ++mi) {
    size_t qb = ((size_t)u * SEQ + qt * 128 + w * 32 + mi * 16 + lc) * HDIM + lq * 8;
    qh[mi][0] = *(const shortx8*)(q_hi + qb);
    qh[mi][1] = *(const shortx8*)(q_hi + qb + 32);
    ql[mi][0] = *(const shortx8*)(q_lo + qb);
    ql[mi][1] = *(const shortx8*)(q_lo + qb + 32);
  }

  shortx8 ONES;
  #pragma unroll
  for (int j = 0; j < 8; ++j) ONES[j] = (short)0x3F80;  // bf16 1.0

  floatx4 O[2][4] = {};
  floatx4 Osum[2] = {};
  float mrow[2][4];
  #pragma unroll
  for (int mi = 0; mi < 2; ++mi)
    #pragma unroll
    for (int r = 0; r < 4; ++r) mrow[mi][r] = -1e30f;
  const float Cs = 11.5415603271f;  // 8 * log2(e)

  // per-lane fixed base pointers for direct B-frag loads
  const u16* Kh_l = k_hi + (size_t)u * SEQ * HDIM + lc * HDIM + lq * 8;
  const u16* Kl_l = k_lo + (size_t)u * SEQ * HDIM + lc * HDIM + lq * 8;
  const u16* Vb_l = vT   + (size_t)u * HDIM * SEQ + lc * SEQ  + lq * 8;

  for (int kc = 0; kc < SEQ; kc += 64) {
    // S = Q.K^T: K B-frags direct from global (batched 8 loads per ks)
    floatx4 S[2][4] = {};
    #pragma unroll
    for (int ks = 0; ks < 2; ++ks) {
      shortx8 kf[4], lf[4];
      #pragma unroll
      for (int nt = 0; nt < 4; ++nt) {
        kf[nt] = *(const shortx8*)(Kh_l + (size_t)(kc + nt * 16) * HDIM + ks * 32);
        lf[nt] = *(const shortx8*)(Kl_l + (size_t)(kc + nt * 16) * HDIM + ks * 32);
      }
      #pragma unroll
      for (int nt = 0; nt < 4; ++nt)
        #pragma unroll
        for (int mi = 0; mi < 2; ++mi) {
          S[mi][nt] = __builtin_amdgcn_mfma_f32_16x16x32_bf16(qh[mi][ks], kf[nt], S[mi][nt], 0, 0, 0);
          S[mi][nt] = __builtin_amdgcn_mfma_f32_16x16x32_bf16(ql[mi][ks], kf[nt], S[mi][nt], 0, 0, 0);
          S[mi][nt] = __builtin_amdgcn_mfma_f32_16x16x32_bf16(qh[mi][ks], lf[nt], S[mi][nt], 0, 0, 0);
        }
    }

    // online softmax; l via ones-column MFMA (Osum)
    #pragma unroll
    for (int mi = 0; mi < 2; ++mi) {
      float alpha[4];
      #pragma unroll
      for (int r = 0; r < 4; ++r) {
        float mc = fmaxf(fmaxf(S[mi][0][r], S[mi][1][r]), fmaxf(S[mi][2][r], S[mi][3][r]));
        mc = swz_max16(mc);
        float mn = fmaxf(mrow[mi][r], mc * Cs);
        alpha[r] = __builtin_amdgcn_exp2f(mrow[mi][r] - mn);
        mrow[mi][r] = mn;
      }
      #pragma unroll
      for (int nt = 0; nt < 4; ++nt)
        #pragma unroll
        for (int r = 0; r < 4; ++r) {
          float e = __builtin_amdgcn_exp2f(fmaf(S[mi][nt][r], Cs, -mrow[mi][r]));
          psw[(mi * 16 + lq * 4 + r) * LDK + nt * 16 + lc] = f2bf_tr(e);
        }
      #pragma unroll
      for (int nt = 0; nt < 4; ++nt)
        #pragma unroll
        for (int r = 0; r < 4; ++r) O[mi][nt][r] *= alpha[r];
      #pragma unroll
      for (int r = 0; r < 4; ++r) Osum[mi][r] *= alpha[r];
    }

    // PV: V B-frags direct from global; P from wave-private LDS
    #pragma unroll
    for (int ks = 0; ks < 2; ++ks) {
      shortx8 vf[4], pf[2];
      #pragma unroll
      for (int nt = 0; nt < 4; ++nt)
        vf[nt] = *(const shortx8*)(Vb_l + (size_t)(nt * 16) * SEQ + kc + ks * 32);
      #pragma unroll
      for (int mi = 0; mi < 2; ++mi)
        pf[mi] = *(const shortx8*)&psw[(mi * 16 + lc) * LDK + ks * 32 + lq * 8];
      #pragma unroll
      for (int nt = 0; nt < 4; ++nt)
        #pragma unroll
        for (int mi = 0; mi < 2; ++mi)
          O[mi][nt] = __builtin_amdgcn_mfma_f32_16x16x32_bf16(pf[mi], vf[nt], O[mi][nt], 0, 0, 0);
      #pragma unroll
      for (int mi = 0; mi < 2; ++mi)
        Osum[mi] = __builtin_amdgcn_mfma_f32_16x16x32_bf16(pf[mi], ONES, Osum[mi], 0, 0, 0);
    }
  }

  int modal = u / 24, b = (u / 12) & 1, h = u % 12;
  #pragma unroll
  for (int mi = 0; mi < 2; ++mi)
    #pragma unroll
    for (int r = 0; r < 4; ++r) {
      float rl = __builtin_amdgcn_rcpf(Osum[mi][r]);
      int qrow = qt * 128 + w * 32 + mi * 16 + lq * 4 + r;
      size_t ob = ((size_t)(modal * RPM + b * SEQ + qrow)) * EMB + h * 64 + lc;
      #pragma unroll
      for (int nt = 0; nt < 4; ++nt)
        attn_out[ob + nt * 16] = f2bf(O[mi][nt][r] * rl);
    }
}

// ---------------- Kernel 4: proj GEMM (pre-split W, reg-prefetch) ----------------
// grid (32 row-tiles, 6 col-tiles, 2 modals)
__global__ __launch_bounds__(256) void k_proj(
    const u16* __restrict__ ao, const u16* __restrict__ wph,
    const float* __restrict__ x1, const float* __restrict__ x2,
    const float* __restrict__ bp1, const float* __restrict__ bp2,
    float* __restrict__ out)
{
  int mt = blockIdx.x, ntile = blockIdx.y, modal = blockIdx.z;
  const float* BP = modal ? bp2 : bp1;
  const float* x  = modal ? x2 : x1;

  __shared__ u16 As[128 * LDA], Ws[128 * LDA];
  int tid = threadIdx.x, lane = tid & 63, w = tid >> 6;
  int wm = (w >> 1) * 64, wn = (w & 1) * 64;
  int lc = lane & 15, lq = lane >> 4;

  floatx4 acc[4][4] = {};
  size_t arow0 = (size_t)(modal * RPM + mt * 128) * EMB;
  int col0 = ntile * 128;
  size_t wrow0 = (size_t)(modal * 768 + col0) * EMB;

  int c0 = tid, c1 = tid + 256;
  int r0 = c0 >> 2, cc0 = (c0 & 3) * 8;
  int r1 = c1 >> 2, cc1 = (c1 & 3) * 8;
  size_t go0 = (size_t)r0 * EMB + cc0, go1 = (size_t)r1 * EMB + cc1;

  shortx8 pA0, pA1, pW0, pW1;
  #define PROJ_LOAD(k0) do { \
    pA0 = *(const shortx8*)(ao + arow0 + go0 + (k0)); \
    pA1 = *(const shortx8*)(ao + arow0 + go1 + (k0)); \
    pW0 = *(const shortx8*)(wph + wrow0 + go0 + (k0)); \
    pW1 = *(const shortx8*)(wph + wrow0 + go1 + (k0)); } while (0)

  PROJ_LOAD(0);
  for (int k0 = 0; k0 < EMB; k0 += 32) {
    *(shortx8*)&As[r0 * LDA + cc0] = pA0;
    *(shortx8*)&As[r1 * LDA + cc1] = pA1;
    *(shortx8*)&Ws[r0 * LDA + cc0] = pW0;
    *(shortx8*)&Ws[r1 * LDA + cc1] = pW1;
    __syncthreads();
    if (k0 + 32 < EMB) PROJ_LOAD(k0 + 32);

    shortx8 af[4], wf[4];
    #pragma unroll
    for (int i = 0; i < 4; ++i) {
      af[i] = *(const shortx8*)&As[(wm + i * 16 + lc) * LDA + lq * 8];
      wf[i] = *(const shortx8*)&Ws[(wn + i * 16 + lc) * LDA + lq * 8];
    }
    #pragma unroll
    for (int i = 0; i < 4; ++i)
      #pragma unroll
      for (int jn = 0; jn < 4; ++jn)
        acc[i][jn] = __builtin_amdgcn_mfma_f32_16x16x32_bf16(af[i], wf[jn], acc[i][jn], 0, 0, 0);
    __syncthreads();
  }
  #undef PROJ_LOAD

  #pragma unroll
  for (int i = 0; i < 4; ++i) {
    int mrow0 = mt * 128 + wm + i * 16 + lq * 4;
    #pragma unroll
    for (int jn = 0; jn < 4; ++jn) {
      int col = col0 + wn + jn * 16 + lc;
      float bias = BP[col];
      #pragma unroll
      for (int r = 0; r < 4; ++r) {
        int mrow = mrow0 + r;
        float val = acc[i][jn][r] + bias + x[(size_t)mrow * EMB + col];
        out[((size_t)(modal * RPM + mrow)) * EMB + col] = val;
      }
    }
  }
}

extern "C" void kernel_launch(void* const* d_in, const int* in_sizes, int n_in,
                              void* d_out, int out_size, void* d_ws, size_t ws_size,
                              hipStream_t stream) {
  const float* modal1 = (const float*)d_in[0];
  const float* modal2 = (const float*)d_in[1];
  const float* ln1_g  = (const float*)d_in[2];
  const float* ln1_b  = (const float*)d_in[3];
  const float* w_qkv1 = (const float*)d_in[4];
  const float* b_qkv1 = (const float*)d_in[5];
  const float* w_proj1= (const float*)d_in[6];
  const float* b_proj1= (const float*)d_in[7];
  const float* ln2_g  = (const float*)d_in[8];
  const float* ln2_b  = (const float*)d_in[9];
  const float* w_qkv2 = (const float*)d_in[10];
  const float* b_qkv2 = (const float*)d_in[11];
  const float* w_proj2= (const float*)d_in[12];
  const float* b_proj2= (const float*)d_in[13];
  float* out = (float*)d_out;

  const size_t BUFE = (size_t)NROW * EMB;       // 6291456 elems
  const size_t WQE  = (size_t)2 * 2304 * EMB;   // 3538944 elems
  u16* xn_hi = (u16*)d_ws;
  u16* xn_lo = xn_hi + BUFE;
  u16* q_hi  = xn_lo + BUFE;
  u16* q_lo  = q_hi + BUFE;
  u16* k_hi  = q_lo + BUFE;
  u16* k_lo  = k_hi + BUFE;
  u16* vT    = k_lo + BUFE;
  u16* wq_h  = vT + BUFE;
  u16* wq_l  = wq_h + WQE;
  u16* attn  = xn_hi;   // xn dead after k_qkv
  u16* wp_h  = q_lo;    // q_lo dead after k_attn

  prep_wq<<<4608, 256, 0, stream>>>(w_qkv1, w_qkv2, wq_h, wq_l);
  k_ln<<<NROW, 256, 0, stream>>>(modal1, modal2, ln1_g, ln1_b, ln2_g, ln2_b, xn_hi, xn_lo);
  dim3 g2(32, 18, 2);
  k_qkv<<<g2, 256, 0, stream>>>(xn_hi, xn_lo, wq_h, wq_l, b_qkv1, b_qkv2,
                                q_hi, q_lo, k_hi, k_lo, vT);
  dim3 g3(48, 16);   // u fastest -> XCD = u%8 fixed across qt
  k_attn<<<g3, 256, 0, stream>>>(q_hi, q_lo, k_hi, k_lo, vT, attn);
  prep_wp<<<1536, 256, 0, stream>>>(w_proj1, w_proj2, wp_h);
  dim3 g4(32, 6, 2);
  k_proj<<<g4, 256, 0, stream>>>(attn, wp_h, modal1, modal2, b_proj1, b_proj2, out);
}

// Round 7
// 426.880 us; speedup vs baseline: 1.3011x; 1.3011x over previous
//
#include <hip/hip_runtime.h>
#include <hip/hip_bf16.h>

// r2: I/O fp32. r3: 605. r4: 407 (k_attn 185; best staging). r5: 429 — compiler
// sank plain prefetch loads (VGPR 124->108 = the tell). r6: 555 — direct-global
// B-frags hit the L1 request-rate wall (16 scattered rows/instr).
// r7: async global_load_lds staging (unsinkable DMA) + XOR-swizzled LDS layouts
// (DMA needs lane-contiguous dest; swizzle the SOURCE address instead of padding).
// k_attn: double-buffered, 1 barrier/iter, LDS=64KB exactly. k_qkv/k_proj: m97-style.

typedef unsigned short u16;
typedef unsigned int   u32;
typedef __attribute__((ext_vector_type(4))) float          floatx4;
typedef __attribute__((ext_vector_type(8))) short          shortx8;

#define EMB   768
#define SEQ   2048
#define NHEAD 12
#define HDIM  64
#define RPM   4096   // rows per modal (B*N)
#define NROW  8192   // total rows (2 modals)
#define NUNIT 48     // modal*B*H units

__device__ __forceinline__ float bf2f(u16 h) {
  union { u32 u; float f; } v; v.u = ((u32)h) << 16; return v.f;
}
__device__ __forceinline__ u16 f2bf(float f) {            // RNE
  union { float f; u32 u; } v; v.f = f;
  u32 r = v.u + 0x7fffu + ((v.u >> 16) & 1u);
  return (u16)(r >> 16);
}
__device__ __forceinline__ u16 f2bf_tr(float f) {         // truncate (P in [0,1])
  union { float f; u32 u; } v; v.f = f;
  return (u16)(v.u >> 16);
}
__device__ __forceinline__ float swz_max16(float v) {     // max over 16-lane group
  union { float f; int i; } a;
  a.f = v; a.i = __builtin_amdgcn_ds_swizzle(a.i, 0x041F); v = fmaxf(v, a.f);
  a.f = v; a.i = __builtin_amdgcn_ds_swizzle(a.i, 0x081F); v = fmaxf(v, a.f);
  a.f = v; a.i = __builtin_amdgcn_ds_swizzle(a.i, 0x101F); v = fmaxf(v, a.f);
  a.f = v; a.i = __builtin_amdgcn_ds_swizzle(a.i, 0x201F); v = fmaxf(v, a.f);
  return v;
}

// async global->LDS DMA, 16B/lane. LDS dest = wave-uniform base + lane*16.
__device__ __forceinline__ void async16(const u16* g, u16* l) {
  __builtin_amdgcn_global_load_lds(
      (const __attribute__((address_space(1))) u32*)g,
      (__attribute__((address_space(3))) u32*)l, 16, 0, 0);
}

// swizzled LDS index (elements): 64-col rows, 8 groups of 8
#define SWZ8(row, lg) (((row) << 6) + ((((lg) ^ ((row) & 7))) << 3))
// swizzled LDS index: 32-col rows, 4 groups of 8
#define SWZ4(row, lg) (((row) << 5) + ((((lg) ^ ((row) & 3))) << 3))

// ---------------- prep: split qkv weights fp32 -> bf16 hi/lo, permuted ----------------
__global__ __launch_bounds__(256) void prep_wq(
    const float* __restrict__ wq1, const float* __restrict__ wq2,
    u16* __restrict__ wh, u16* __restrict__ wl)
{
  int bx = blockIdx.x;                  // 0..4607
  int modal = bx / 2304, rowp = bx % 2304;
  int typ = rowp / 768, hd = rowp % 768;
  const float* W = (modal ? wq2 : wq1) + (size_t)(hd * 3 + typ) * EMB;
  size_t dst = (size_t)bx * EMB;
  int t = threadIdx.x;
  #pragma unroll
  for (int i = 0; i < 3; ++i) {
    int e = t + i * 256;
    float v = W[e];
    u16 h = f2bf(v);
    wh[dst + e] = h;
    wl[dst + e] = f2bf(v - bf2f(h));
  }
}

__global__ __launch_bounds__(256) void prep_wp(
    const float* __restrict__ wp1, const float* __restrict__ wp2,
    u16* __restrict__ wh)
{
  int bx = blockIdx.x;                  // 0..1535
  int modal = bx / 768, row = bx % 768;
  const float* W = (modal ? wp2 : wp1) + (size_t)row * EMB;
  size_t dst = (size_t)bx * EMB;
  int t = threadIdx.x;
  #pragma unroll
  for (int i = 0; i < 3; ++i) {
    int e = t + i * 256;
    wh[dst + e] = f2bf(W[e]);
  }
}

// ---------------- Kernel 1: LayerNorm (fp32 in) + hi/lo bf16 split ----------------
__global__ __launch_bounds__(256) void k_ln(
    const float* __restrict__ x1, const float* __restrict__ x2,
    const float* __restrict__ g1, const float* __restrict__ b1,
    const float* __restrict__ g2, const float* __restrict__ b2,
    u16* __restrict__ xn_hi, u16* __restrict__ xn_lo)
{
  int row = blockIdx.x;                 // 0..8191, modal-major
  int modal = row >> 12;
  const float* x = modal ? x2 : x1;
  const float* g = modal ? g2 : g1;
  const float* bb = modal ? b2 : b1;
  int r = row & (RPM - 1);
  const float* xr = x + (size_t)r * EMB;
  int t = threadIdx.x;
  float v0 = xr[t], v1 = xr[t + 256], v2 = xr[t + 512];
  float s = v0 + v1 + v2;
  float s2 = v0 * v0 + v1 * v1 + v2 * v2;
  #pragma unroll
  for (int m = 1; m < 64; m <<= 1) { s += __shfl_xor(s, m); s2 += __shfl_xor(s2, m); }
  __shared__ float ls[4], ls2[4];
  int w = t >> 6;
  if ((t & 63) == 0) { ls[w] = s; ls2[w] = s2; }
  __syncthreads();
  s = ls[0] + ls[1] + ls[2] + ls[3];
  s2 = ls2[0] + ls2[1] + ls2[2] + ls2[3];
  float mu = s * (1.0f / EMB);
  float var = s2 * (1.0f / EMB) - mu * mu;
  float rs = rsqrtf(var + 1e-5f);
  size_t base = (size_t)row * EMB;
  float vv[3] = { v0, v1, v2 };
  #pragma unroll
  for (int i = 0; i < 3; ++i) {
    int e = t + i * 256;
    float xn = (vv[i] - mu) * rs * g[e] + bb[e];
    u16 h = f2bf(xn);
    xn_hi[base + e] = h;
    xn_lo[base + e] = f2bf(xn - bf2f(h));
  }
}

// ---------------- Kernel 2: QKV GEMM — async DMA staging (m97-style) ----------------
// grid (32 row-tiles, 18 col-tiles, 2 modals), 256 thr. Tile 128x128, BK=32.
__global__ __launch_bounds__(256) void k_qkv(
    const u16* __restrict__ xn_hi, const u16* __restrict__ xn_lo,
    const u16* __restrict__ wqh, const u16* __restrict__ wql,
    const float* __restrict__ bq1, const float* __restrict__ bq2,
    u16* __restrict__ q_hi, u16* __restrict__ q_lo,
    u16* __restrict__ k_hi, u16* __restrict__ k_lo,
    u16* __restrict__ vT)
{
  int mt = blockIdx.x, ntile = blockIdx.y, modal = blockIdx.z;
  const float* BQ = modal ? bq2 : bq1;
  int typ = ntile / 6;            // 0=q 1=k 2=v
  int hd0 = (ntile % 6) * 128;

  __shared__ u16 Ah[128 * 32], Al[128 * 32], Bh[128 * 32], Bl[128 * 32];

  int tid = threadIdx.x, lane = tid & 63, w = tid >> 6;
  int wm = (w >> 1) * 64, wn = (w & 1) * 64;
  int lc = lane & 15, lq = lane >> 4;

  floatx4 acc[4][4] = {};
  size_t arow0 = (size_t)(modal * RPM + mt * 128) * EMB;
  size_t wrow0 = (size_t)(modal * 2304 + typ * 768 + hd0) * EMB;

  // DMA geometry: wave w stages rows [w*32, w*32+32), 2 segs of 16 rows.
  // lane i -> row seg-base + (i>>2), phys group i&3, logical group (i&3)^((i>>2)&3)
  int rsub = lane >> 2;
  int g4 = (lane & 3) ^ (rsub & 3);
  const u16 *sA[2], *sAl[2], *sW[2], *sWl[2];
  int ldst[2];
  #pragma unroll
  for (int seg = 0; seg < 2; ++seg) {
    int row = w * 32 + seg * 16 + rsub;
    sA[seg]  = xn_hi + arow0 + (size_t)row * EMB + g4 * 8;
    sAl[seg] = xn_lo + arow0 + (size_t)row * EMB + g4 * 8;
    sW[seg]  = wqh + wrow0 + (size_t)row * EMB + g4 * 8;
    sWl[seg] = wql + wrow0 + (size_t)row * EMB + g4 * 8;
    ldst[seg] = (w * 32 + seg * 16) * 32;
  }

  for (int k0 = 0; k0 < EMB; k0 += 32) {
    #pragma unroll
    for (int seg = 0; seg < 2; ++seg) {
      async16(sA[seg] + k0, &Ah[ldst[seg]]);
      async16(sW[seg] + k0, &Bh[ldst[seg]]);
      if (typ != 2) {
        async16(sAl[seg] + k0, &Al[ldst[seg]]);
        async16(sWl[seg] + k0, &Bl[ldst[seg]]);
      }
    }
    __syncthreads();   // DMA drained

    shortx8 ah[4], al[4], wh[4], wl[4];
    #pragma unroll
    for (int i = 0; i < 4; ++i) {
      ah[i] = *(const shortx8*)&Ah[SWZ4(wm + i * 16 + lc, lq)];
      wh[i] = *(const shortx8*)&Bh[SWZ4(wn + i * 16 + lc, lq)];
      if (typ != 2) {
        al[i] = *(const shortx8*)&Al[SWZ4(wm + i * 16 + lc, lq)];
        wl[i] = *(const shortx8*)&Bl[SWZ4(wn + i * 16 + lc, lq)];
      }
    }
    #pragma unroll
    for (int i = 0; i < 4; ++i)
      #pragma unroll
      for (int jn = 0; jn < 4; ++jn) {
        acc[i][jn] = __builtin_amdgcn_mfma_f32_16x16x32_bf16(ah[i], wh[jn], acc[i][jn], 0, 0, 0);
        if (typ != 2) {
          acc[i][jn] = __builtin_amdgcn_mfma_f32_16x16x32_bf16(al[i], wh[jn], acc[i][jn], 0, 0, 0);
          acc[i][jn] = __builtin_amdgcn_mfma_f32_16x16x32_bf16(ah[i], wl[jn], acc[i][jn], 0, 0, 0);
        }
      }
    __syncthreads();   // reads done before next DMA overwrites
  }

  #pragma unroll
  for (int i = 0; i < 4; ++i) {
    int mrow0 = mt * 128 + wm + i * 16 + lq * 4;
    #pragma unroll
    for (int jn = 0; jn < 4; ++jn) {
      int colp = hd0 + wn + jn * 16 + lc;          // hd index [0,768)
      int h = colp >> 6, d = colp & 63;
      float bias = BQ[colp * 3 + typ];
      #pragma unroll
      for (int r = 0; r < 4; ++r) {
        int mrow = mrow0 + r;
        int b = mrow >> 11, nq = mrow & (SEQ - 1);
        int uu = modal * 24 + b * 12 + h;
        float val = acc[i][jn][r] + bias;
        if (typ == 0) {
          size_t o = ((size_t)uu * SEQ + nq) * HDIM + d;
          u16 hh = f2bf(val); q_hi[o] = hh; q_lo[o] = f2bf(val - bf2f(hh));
        } else if (typ == 1) {
          size_t o = ((size_t)uu * SEQ + nq) * HDIM + d;
          u16 hh = f2bf(val); k_hi[o] = hh; k_lo[o] = f2bf(val - bf2f(hh));
        } else {
          vT[((size_t)uu * HDIM + d) * SEQ + nq] = f2bf(val);
        }
      }
    }
  }
}

// ---------------- Kernel 3: flash attention — async DMA, double-buffered ----------------
// grid (48 units, 16 q-tiles): XCD = u%8 fixed -> per-unit K/V L2-resident.
// LDS: KV dbuf 48KB + swizzled Ps 16KB = 64KB exactly. 1 barrier per chunk.
__global__ __launch_bounds__(256) void k_attn(
    const u16* __restrict__ q_hi, const u16* __restrict__ q_lo,
    const u16* __restrict__ k_hi, const u16* __restrict__ k_lo,
    const u16* __restrict__ vT, u16* __restrict__ attn_out)
{
  int u = blockIdx.x, qt = blockIdx.y;
  __shared__ u16 KV[2][3][64 * 64];     // [buf][Kh,Kl,V][swizzled 64x64]
  __shared__ u16 Ps[4][32 * 64];        // swizzled, wave-private

  int tid = threadIdx.x, lane = tid & 63, w = tid >> 6;
  int lc = lane & 15, lq = lane >> 4;
  u16* psw = &Ps[w][0];

  // Q fragments: 2 m-tiles x 2 k-slices, hi+lo (A-layout: m=lc, k=lq*8+j)
  shortx8 qh[2][2], ql[2][2];
  #pragma unroll
  for (int mi = 0; mi < 2; ++mi) {
    size_t qb = ((size_t)u * SEQ + qt * 128 + w * 32 + mi * 16 + lc) * HDIM + lq * 8;
    qh[mi][0] = *(const shortx8*)(q_hi + qb);
    qh[mi][1] = *(const shortx8*)(q_hi + qb + 32);
    ql[mi][0] = *(const shortx8*)(q_lo + qb);
    ql[mi][1] = *(const shortx8*)(q_lo + qb + 32);
  }

  shortx8 ONES;
  #pragma unroll
  for (int j = 0; j < 8; ++j) ONES[j] = (short)0x3F80;  // bf16 1.0

  floatx4 O[2][4] = {};
  floatx4 Osum[2] = {};
  float mrow[2][4];
  #pragma unroll
  for (int mi = 0; mi < 2; ++mi)
    #pragma unroll
    for (int r = 0; r < 4; ++r) mrow[mi][r] = -1e30f;
  const float Cs = 11.5415603271f;  // 8 * log2(e)

  // DMA geometry: wave w stages rows [w*16, w*16+16) of each array, 2 segs of 8.
  // lane i -> row seg-base + (i>>3), phys group i&7, logical group (i&7)^((i>>3)&7)
  int rsub = lane >> 3;
  int g8 = (lane & 7) ^ rsub;
  const u16 *sKh[2], *sKl[2], *sV[2];
  int ldst[2];
  #pragma unroll
  for (int seg = 0; seg < 2; ++seg) {
    int row = w * 16 + seg * 8 + rsub;
    sKh[seg] = k_hi + ((size_t)u * SEQ + row) * HDIM + g8 * 8;
    sKl[seg] = k_lo + ((size_t)u * SEQ + row) * HDIM + g8 * 8;
    sV[seg]  = vT + ((size_t)u * HDIM + row) * SEQ + g8 * 8;
    ldst[seg] = (w * 16 + seg * 8) * 64;
  }

  // prologue: chunk 0 -> buf 0
  #pragma unroll
  for (int seg = 0; seg < 2; ++seg) {
    async16(sKh[seg], &KV[0][0][ldst[seg]]);
    async16(sKl[seg], &KV[0][1][ldst[seg]]);
    async16(sV[seg],  &KV[0][2][ldst[seg]]);
  }
  __syncthreads();

  for (int kc = 0; kc < SEQ; kc += 64) {
    int b = (kc >> 6) & 1;
    if (kc + 64 < SEQ) {                  // DMA next chunk -> other buf, in flight
      int nb = b ^ 1;                     // across the whole compute below
      #pragma unroll
      for (int seg = 0; seg < 2; ++seg) {
        async16(sKh[seg] + (size_t)(kc + 64) * HDIM, &KV[nb][0][ldst[seg]]);
        async16(sKl[seg] + (size_t)(kc + 64) * HDIM, &KV[nb][1][ldst[seg]]);
        async16(sV[seg] + (kc + 64),                 &KV[nb][2][ldst[seg]]);
      }
    }

    // S = Q.K^T, 3-pass hi/lo, swizzled B-frag reads
    floatx4 S[2][4] = {};
    #pragma unroll
    for (int nt = 0; nt < 4; ++nt)
      #pragma unroll
      for (int ks = 0; ks < 2; ++ks) {
        shortx8 kf = *(const shortx8*)&KV[b][0][SWZ8(nt * 16 + lc, ks * 4 + lq)];
        shortx8 lf = *(const shortx8*)&KV[b][1][SWZ8(nt * 16 + lc, ks * 4 + lq)];
        #pragma unroll
        for (int mi = 0; mi < 2; ++mi) {
          S[mi][nt] = __builtin_amdgcn_mfma_f32_16x16x32_bf16(qh[mi][ks], kf, S[mi][nt], 0, 0, 0);
          S[mi][nt] = __builtin_amdgcn_mfma_f32_16x16x32_bf16(ql[mi][ks], kf, S[mi][nt], 0, 0, 0);
          S[mi][nt] = __builtin_amdgcn_mfma_f32_16x16x32_bf16(qh[mi][ks], lf, S[mi][nt], 0, 0, 0);
        }
      }

    // online softmax; l via ones-column MFMA (Osum)
    #pragma unroll
    for (int mi = 0; mi < 2; ++mi) {
      float alpha[4];
      #pragma unroll
      for (int r = 0; r < 4; ++r) {
        float mc = fmaxf(fmaxf(S[mi][0][r], S[mi][1][r]), fmaxf(S[mi][2][r], S[mi][3][r]));
        mc = swz_max16(mc);
        float mn = fmaxf(mrow[mi][r], mc * Cs);
        alpha[r] = __builtin_amdgcn_exp2f(mrow[mi][r] - mn);
        mrow[mi][r] = mn;
      }
      #pragma unroll
      for (int nt = 0; nt < 4; ++nt)
        #pragma unroll
        for (int r = 0; r < 4; ++r) {
          float e = __builtin_amdgcn_exp2f(fmaf(S[mi][nt][r], Cs, -mrow[mi][r]));
          int prow = mi * 16 + lq * 4 + r;
          int pcol = nt * 16 + lc;        // logical col; swizzle group (pcol>>3)^(prow&7)
          psw[(prow << 6) + ((((pcol >> 3) ^ (prow & 7))) << 3) + (pcol & 7)] = f2bf_tr(e);
        }
      #pragma unroll
      for (int nt = 0; nt < 4; ++nt)
        #pragma unroll
        for (int r = 0; r < 4; ++r) O[mi][nt][r] *= alpha[r];
      #pragma unroll
      for (int r = 0; r < 4; ++r) Osum[mi][r] *= alpha[r];
    }

    // PV (Ps wave-private; DS ops in-order within wave)
    #pragma unroll
    for (int ks = 0; ks < 2; ++ks) {
      shortx8 pf[2];
      #pragma unroll
      for (int mi = 0; mi < 2; ++mi)
        pf[mi] = *(const shortx8*)&psw[SWZ8(mi * 16 + lc, ks * 4 + lq)];
      #pragma unroll
      for (int nt = 0; nt < 4; ++nt) {
        shortx8 vf = *(const shortx8*)&KV[b][2][SWZ8(nt * 16 + lc, ks * 4 + lq)];
        #pragma unroll
        for (int mi = 0; mi < 2; ++mi)
          O[mi][nt] = __builtin_amdgcn_mfma_f32_16x16x32_bf16(pf[mi], vf, O[mi][nt], 0, 0, 0);
      }
      #pragma unroll
      for (int mi = 0; mi < 2; ++mi)
        Osum[mi] = __builtin_amdgcn_mfma_f32_16x16x32_bf16(pf[mi], ONES, Osum[mi], 0, 0, 0);
    }
    __syncthreads();   // drains next-chunk DMA (in flight all this time) + syncs bufs
  }

  int modal = u / 24, b2 = (u / 12) & 1, h = u % 12;
  #pragma unroll
  for (int mi = 0; mi < 2; ++mi)
    #pragma unroll
    for (int r = 0; r < 4; ++r) {
      float rl = __builtin_amdgcn_rcpf(Osum[mi][r]);
      int qrow = qt * 128 + w * 32 + mi * 16 + lq * 4 + r;
      size_t ob = ((size_t)(modal * RPM + b2 * SEQ + qrow)) * EMB + h * 64 + lc;
      #pragma unroll
      for (int nt = 0; nt < 4; ++nt)
        attn_out[ob + nt * 16] = f2bf(O[mi][nt][r] * rl);
    }
}

// ---------------- Kernel 4: proj GEMM — async DMA staging ----------------
// grid (32 row-tiles, 6 col-tiles, 2 modals)
__global__ __launch_bounds__(256) void k_proj(
    const u16* __restrict__ ao, const u16* __restrict__ wph,
    const float* __restrict__ x1, const float* __restrict__ x2,
    const float* __restrict__ bp1, const float* __restrict__ bp2,
    float* __restrict__ out)
{
  int mt = blockIdx.x, ntile = blockIdx.y, modal = blockIdx.z;
  const float* BP = modal ? bp2 : bp1;
  const float* x  = modal ? x2 : x1;

  __shared__ u16 As[128 * 32], Ws[128 * 32];
  int tid = threadIdx.x, lane = tid & 63, w = tid >> 6;
  int wm = (w >> 1) * 64, wn = (w & 1) * 64;
  int lc = lane & 15, lq = lane >> 4;

  floatx4 acc[4][4] = {};
  size_t arow0 = (size_t)(modal * RPM + mt * 128) * EMB;
  int col0 = ntile * 128;
  size_t wrow0 = (size_t)(modal * 768 + col0) * EMB;

  int rsub = lane >> 2;
  int g4 = (lane & 3) ^ (rsub & 3);
  const u16 *sA[2], *sW[2];
  int ldst[2];
  #pragma unroll
  for (int seg = 0; seg < 2; ++seg) {
    int row = w * 32 + seg * 16 + rsub;
    sA[seg] = ao + arow0 + (size_t)row * EMB + g4 * 8;
    sW[seg] = wph + wrow0 + (size_t)row * EMB + g4 * 8;
    ldst[seg] = (w * 32 + seg * 16) * 32;
  }

  for (int k0 = 0; k0 < EMB; k0 += 32) {
    #pragma unroll
    for (int seg = 0; seg < 2; ++seg) {
      async16(sA[seg] + k0, &As[ldst[seg]]);
      async16(sW[seg] + k0, &Ws[ldst[seg]]);
    }
    __syncthreads();

    shortx8 af[4], wf[4];
    #pragma unroll
    for (int i = 0; i < 4; ++i) {
      af[i] = *(const shortx8*)&As[SWZ4(wm + i * 16 + lc, lq)];
      wf[i] = *(const shortx8*)&Ws[SWZ4(wn + i * 16 + lc, lq)];
    }
    #pragma unroll
    for (int i = 0; i < 4; ++i)
      #pragma unroll
      for (int jn = 0; jn < 4; ++jn)
        acc[i][jn] = __builtin_amdgcn_mfma_f32_16x16x32_bf16(af[i], wf[jn], acc[i][jn], 0, 0, 0);
    __syncthreads();
  }

  #pragma unroll
  for (int i = 0; i < 4; ++i) {
    int mrow0 = mt * 128 + wm + i * 16 + lq * 4;
    #pragma unroll
    for (int jn = 0; jn < 4; ++jn) {
      int col = col0 + wn + jn * 16 + lc;
      float bias = BP[col];
      #pragma unroll
      for (int r = 0; r < 4; ++r) {
        int mrow = mrow0 + r;
        float val = acc[i][jn][r] + bias + x[(size_t)mrow * EMB + col];
        out[((size_t)(modal * RPM + mrow)) * EMB + col] = val;
      }
    }
  }
}

extern "C" void kernel_launch(void* const* d_in, const int* in_sizes, int n_in,
                              void* d_out, int out_size, void* d_ws, size_t ws_size,
                              hipStream_t stream) {
  const float* modal1 = (const float*)d_in[0];
  const float* modal2 = (const float*)d_in[1];
  const float* ln1_g  = (const float*)d_in[2];
  const float* ln1_b  = (const float*)d_in[3];
  const float* w_qkv1 = (const float*)d_in[4];
  const float* b_qkv1 = (const float*)d_in[5];
  const float* w_proj1= (const float*)d_in[6];
  const float* b_proj1= (const float*)d_in[7];
  const float* ln2_g  = (const float*)d_in[8];
  const float* ln2_b  = (const float*)d_in[9];
  const float* w_qkv2 = (const float*)d_in[10];
  const float* b_qkv2 = (const float*)d_in[11];
  const float* w_proj2= (const float*)d_in[12];
  const float* b_proj2= (const float*)d_in[13];
  float* out = (float*)d_out;

  const size_t BUFE = (size_t)NROW * EMB;       // 6291456 elems
  const size_t WQE  = (size_t)2 * 2304 * EMB;   // 3538944 elems
  u16* xn_hi = (u16*)d_ws;
  u16* xn_lo = xn_hi + BUFE;
  u16* q_hi  = xn_lo + BUFE;
  u16* q_lo  = q_hi + BUFE;
  u16* k_hi  = q_lo + BUFE;
  u16* k_lo  = k_hi + BUFE;
  u16* vT    = k_lo + BUFE;
  u16* wq_h  = vT + BUFE;
  u16* wq_l  = wq_h + WQE;
  u16* attn  = xn_hi;   // xn dead after k_qkv
  u16* wp_h  = q_lo;    // q_lo dead after k_attn

  prep_wq<<<4608, 256, 0, stream>>>(w_qkv1, w_qkv2, wq_h, wq_l);
  k_ln<<<NROW, 256, 0, stream>>>(modal1, modal2, ln1_g, ln1_b, ln2_g, ln2_b, xn_hi, xn_lo);
  dim3 g2(32, 18, 2);
  k_qkv<<<g2, 256, 0, stream>>>(xn_hi, xn_lo, wq_h, wq_l, b_qkv1, b_qkv2,
                                q_hi, q_lo, k_hi, k_lo, vT);
  dim3 g3(48, 16);   // u fastest -> XCD = u%8 fixed across qt
  k_attn<<<g3, 256, 0, stream>>>(q_hi, q_lo, k_hi, k_lo, vT, attn);
  prep_wp<<<1536, 256, 0, stream>>>(w_proj1, w_proj2, wp_h);
  dim3 g4(32, 6, 2);
  k_proj<<<g4, 256, 0, stream>>>(attn, wp_h, modal1, modal2, b_proj1, b_proj2, out);
}